// Round 6
// baseline (485.857 us; speedup 1.0000x reference)
//
#include <hip/hip_runtime.h>
#include <hip/hip_bf16.h>
#include <hip/hip_cooperative_groups.h>
#include <math.h>

namespace cg = cooperative_groups;

// B=128, F_IN=1000, D=512, K=10, C=5, T=1000, TAU=0.1
// Contraction: logits_s[b,t,k] = sum_c v[b,c,t]*M[b,c,k], M = h @ W_mlp.
// ONE cooperative kernel, 5 phases, 4 grid syncs (R5's lean decomposition,
// zero node-serialization overhead). Fallback: R5's 5-kernel chain if the
// cooperative launch is rejected (e.g. by graph capture).

#define NBLK 640
#define NTHR 256

__global__ __launch_bounds__(256, 3) void mega(
    const float* __restrict__ feats,   const float* __restrict__ W_adapt,
    const float* __restrict__ b_adapt, const float* __restrict__ W_ch,
    const float* __restrict__ b_ch,    const float* __restrict__ W_gate,
    const float* __restrict__ b_gate,  const float* __restrict__ W_mlp,
    const float* __restrict__ b_mlp,   const float* __restrict__ gumbel,
    float* __restrict__ pA, float* __restrict__ r_b, float* __restrict__ hT,
    float* __restrict__ p,  float* __restrict__ M,
    float* __restrict__ out_rs, float* __restrict__ out_gt, float* __restrict__ out_pt)
{
    cg::grid_group grid = cg::this_grid();
    __shared__ float rbs[8 * 64];
    __shared__ float red[4][11];
    __shared__ float spv[5], sM[50];
    const int tid = threadIdx.x;
    const int bid = blockIdx.x;

    // ---------- P1: adapt partials pA[s][b][e] (blocks 0-319); hT=bias (320-639)
    if (bid < 320) {
        int s = bid / 32, bt = bid % 32;
        int b0 = bt * 4, k0 = s * 100, e2 = tid * 2;
        float2 acc[4] = {};
        #pragma unroll 2
        for (int k = 0; k < 100; ++k) {
            float2 w = *(const float2*)&W_adapt[(k0 + k) * 512 + e2];
            #pragma unroll
            for (int j = 0; j < 4; ++j) {
                float f = feats[(b0 + j) * 1000 + k0 + k];   // wave-uniform
                acc[j].x = fmaf(f, w.x, acc[j].x);
                acc[j].y = fmaf(f, w.y, acc[j].y);
            }
        }
        #pragma unroll
        for (int j = 0; j < 4; ++j)
            *(float2*)&pA[(s * 128 + b0 + j) * 512 + e2] = acc[j];
    } else {
        // hT[(c*128+b)*512+e] = b_ch[c*512+e]; 327680 elems over 81920 threads
        int idx = (bid - 320) * NTHR + tid;
        #pragma unroll
        for (int it = 0; it < 4; ++it) {
            int i = idx + it * 81920;
            hT[i] = b_ch[((i >> 16) * 512) + (i & 511)];
        }
    }
    __threadfence();
    grid.sync();

    // ---------- P2: r_b = relu(sum_s pA + b_adapt)  (first 65536 threads)
    {
        int gid = bid * NTHR + tid;
        if (gid < 65536) {
            float acc = b_adapt[gid & 511];
            #pragma unroll
            for (int sp = 0; sp < 10; ++sp) acc += pA[sp * 65536 + gid];
            r_b[gid] = fmaxf(acc, 0.f);
        }
    }
    __threadfence();
    grid.sync();

    // ---------- P3: channel GEMM, d-chunk 64, atomicAdd into hT
    {
        int c = bid % 5, r = bid / 5;
        int ds = r & 7, bt = r >> 3;
        int b0 = bt * 8, d0 = ds * 64;
        #pragma unroll
        for (int it = 0; it < 2; ++it) {
            int idx = it * 256 + tid;            // j*64 + d
            rbs[idx] = r_b[(b0 + (idx >> 6)) * 512 + d0 + (idx & 63)];
        }
        __syncthreads();
        int e2 = tid * 2;
        const float* wb = &W_ch[((size_t)(c * 512 + d0)) * 512 + e2];
        float2 acc[8] = {};
        #pragma unroll 4
        for (int d = 0; d < 64; ++d) {
            float2 w = *(const float2*)&wb[(size_t)d * 512];
            #pragma unroll
            for (int j = 0; j < 8; ++j) {
                float rv = rbs[j * 64 + d];      // LDS broadcast
                acc[j].x = fmaf(rv, w.x, acc[j].x);
                acc[j].y = fmaf(rv, w.y, acc[j].y);
            }
        }
        #pragma unroll
        for (int j = 0; j < 8; ++j) {
            float* dst = &hT[(c * 128 + b0 + j) * 512 + e2];
            atomicAdd(dst,     acc[j].x);
            atomicAdd(dst + 1, acc[j].y);
        }
    }
    grid.sync();

    // ---------- P4: gate + M, one block per (b,c) pair
    {
        int b = bid / 5, c = bid % 5;
        int e2 = tid * 2;
        float2 hv = *(const float2*)&hT[(c * 128 + b) * 512 + e2];
        float hx = fmaxf(hv.x, 0.f), hy = fmaxf(hv.y, 0.f);
        float2 wg = *(const float2*)&W_gate[c * 512 + e2];
        float gs = hx * wg.x + hy * wg.y;
        float am[10];
        const float* wm = &W_mlp[e2 * 10];
        #pragma unroll
        for (int k = 0; k < 10; ++k) am[k] = hx * wm[k] + hy * wm[10 + k];
        #pragma unroll
        for (int off = 32; off; off >>= 1) {
            gs += __shfl_xor(gs, off);
            #pragma unroll
            for (int k = 0; k < 10; ++k) am[k] += __shfl_xor(am[k], off);
        }
        int wv = tid >> 6;
        if ((tid & 63) == 0) {
            red[wv][0] = gs;
            #pragma unroll
            for (int k = 0; k < 10; ++k) red[wv][1 + k] = am[k];
        }
        __syncthreads();
        if (tid == 0) {
            float g = red[0][0] + red[1][0] + red[2][0] + red[3][0];
            float pv = 1.f / (1.f + __expf(-(g + b_gate[c])));
            p[b * 5 + c] = pv;
            out_pt[b * 5 + c] = pv;
            #pragma unroll
            for (int k = 0; k < 10; ++k)
                M[(b * 5 + c) * 10 + k] =
                    red[0][1 + k] + red[1][1 + k] + red[2][1 + k] + red[3][1 + k];
        }
    }
    __threadfence();
    grid.sync();

    // ---------- P5: epilogue, 512 tile-blocks (tc 4, b 128)
    if (bid < 512) {
        int tc = bid & 3, b = bid >> 2;
        if (tid < 50) sM[tid] = M[b * 50 + tid];
        if (tid < 5)  spv[tid] = p[b * 5 + tid];
        __syncthreads();
        int t = tc * 256 + tid;
        if (t < 1000) {
            float ex[5], ssum = 0.f;
            #pragma unroll
            for (int c = 0; c < 5; ++c) {
                float2 gu = *(const float2*)&gumbel[(size_t)(((b * 5 + c) * 1000) + t) * 2];
                float arg = (2.f * spv[c] - 1.f + gu.y - gu.x) * 10.0f;  // /tau
                float gt  = 1.f / (1.f + __expf(-arg));
                out_gt[(b * 5 + c) * 1000 + t] = gt;
                float e = __expf(gt);
                ex[c] = e; ssum += e;
            }
            float inv = 1.f / ssum;
            float lg[10];
            #pragma unroll
            for (int k = 0; k < 10; ++k) lg[k] = b_mlp[k];
            #pragma unroll
            for (int c = 0; c < 5; ++c) {
                float v = ex[c] * inv;
                #pragma unroll
                for (int k = 0; k < 10; ++k) lg[k] = fmaf(v, sM[c * 10 + k], lg[k]);
            }
            float mx = 0.f;
            #pragma unroll
            for (int k = 0; k < 10; ++k) { lg[k] = fmaxf(lg[k], 0.f); mx = fmaxf(mx, lg[k]); }
            float se = 0.f;
            #pragma unroll
            for (int k = 0; k < 10; ++k) { lg[k] = __expf(lg[k] - mx); se += lg[k]; }
            float invs = 1.f / se;
            float2 outv[5];
            #pragma unroll
            for (int k = 0; k < 10; ++k) ((float*)outv)[k] = lg[k] * invs;
            float2* dst = (float2*)&out_rs[(size_t)t * 1280 + b * 10];
            #pragma unroll
            for (int j = 0; j < 5; ++j) dst[j] = outv[j];
        }
    }
}

// ======================= fallback: R5 5-kernel chain =========================
__global__ __launch_bounds__(256) void kA(const float* __restrict__ feats,
                                          const float* __restrict__ W_adapt,
                                          float* __restrict__ pA) {
    int b0 = blockIdx.x * 4;
    int s  = blockIdx.y;
    int k0 = s * 100;
    int e2 = threadIdx.x * 2;
    float2 acc[4] = {};
    #pragma unroll 2
    for (int k = 0; k < 100; ++k) {
        float2 w = *(const float2*)&W_adapt[(k0 + k) * 512 + e2];
        #pragma unroll
        for (int j = 0; j < 4; ++j) {
            float f = feats[(b0 + j) * 1000 + k0 + k];
            acc[j].x = fmaf(f, w.x, acc[j].x);
            acc[j].y = fmaf(f, w.y, acc[j].y);
        }
    }
    #pragma unroll
    for (int j = 0; j < 4; ++j)
        *(float2*)&pA[(s * 128 + b0 + j) * 512 + e2] = acc[j];
}

__global__ __launch_bounds__(256) void kRA(const float* __restrict__ pA,
                                           const float* __restrict__ b_adapt,
                                           const float* __restrict__ b_ch,
                                           float* __restrict__ r_b,
                                           float* __restrict__ hT) {
    int i = blockIdx.x * 256 + threadIdx.x;
    int e = i & 511;
    float acc = b_adapt[e];
    #pragma unroll
    for (int s = 0; s < 10; ++s) acc += pA[s * 65536 + i];
    r_b[i] = fmaxf(acc, 0.f);
    #pragma unroll
    for (int c = 0; c < 5; ++c) hT[c * 65536 + i] = b_ch[c * 512 + e];
}

__global__ __launch_bounds__(256) void kB(const float* __restrict__ r_b,
                                          const float* __restrict__ W_ch,
                                          float* __restrict__ hT) {
    __shared__ float rbs2[8 * 128];
    int b0 = blockIdx.x * 8;
    int d0 = blockIdx.y * 128;
    int c  = blockIdx.z;
    int tid = threadIdx.x;
    #pragma unroll
    for (int it = 0; it < 4; ++it) {
        int idx = it * 256 + tid;
        rbs2[idx] = r_b[(b0 + (idx >> 7)) * 512 + d0 + (idx & 127)];
    }
    __syncthreads();
    int e2 = tid * 2;
    const float* wb = &W_ch[((size_t)(c * 512 + d0)) * 512 + e2];
    float2 acc[8] = {};
    #pragma unroll 4
    for (int d = 0; d < 128; ++d) {
        float2 w = *(const float2*)&wb[(size_t)d * 512];
        #pragma unroll
        for (int j = 0; j < 8; ++j) {
            float r = rbs2[j * 128 + d];
            acc[j].x = fmaf(r, w.x, acc[j].x);
            acc[j].y = fmaf(r, w.y, acc[j].y);
        }
    }
    #pragma unroll
    for (int j = 0; j < 8; ++j) {
        float* dst = &hT[(c * 128 + b0 + j) * 512 + e2];
        atomicAdd(dst,     acc[j].x);
        atomicAdd(dst + 1, acc[j].y);
    }
}

__global__ __launch_bounds__(256) void kG(const float* __restrict__ hT,
                                          const float* __restrict__ W_gate,
                                          const float* __restrict__ W_mlp,
                                          const float* __restrict__ b_gate,
                                          float* __restrict__ p,
                                          float* __restrict__ M,
                                          float* __restrict__ out_pt) {
    int wv = threadIdx.x >> 6, lane = threadIdx.x & 63;
    int pair = blockIdx.x * 4 + wv;
    int b = pair / 5, c = pair % 5;
    float gs = 0.f, am[10] = {};
    #pragma unroll
    for (int i = 0; i < 8; ++i) {
        int e = i * 64 + lane;
        float h = fmaxf(hT[(c * 128 + b) * 512 + e], 0.f);
        gs = fmaf(h, W_gate[c * 512 + e], gs);
        const float* wm = &W_mlp[e * 10];
        #pragma unroll
        for (int k = 0; k < 10; ++k) am[k] = fmaf(h, wm[k], am[k]);
    }
    #pragma unroll
    for (int off = 32; off; off >>= 1) {
        gs += __shfl_xor(gs, off);
        #pragma unroll
        for (int k = 0; k < 10; ++k) am[k] += __shfl_xor(am[k], off);
    }
    if (lane == 0) {
        float pv = 1.f / (1.f + __expf(-(gs + b_gate[c])));
        p[b * 5 + c] = pv;
        out_pt[b * 5 + c] = pv;
        #pragma unroll
        for (int k = 0; k < 10; ++k) M[(b * 5 + c) * 10 + k] = am[k];
    }
}

__global__ __launch_bounds__(256) void kC(const float* __restrict__ p,
                                          const float* __restrict__ M,
                                          const float* __restrict__ b_mlp,
                                          const float* __restrict__ gumbel,
                                          float* __restrict__ out_rs,
                                          float* __restrict__ out_gt) {
    __shared__ float spv[5];
    __shared__ float sM[50];
    int tid = threadIdx.x;
    int b = blockIdx.y;
    if (tid < 50) sM[tid] = M[b * 50 + tid];
    if (tid < 5)  spv[tid] = p[b * 5 + tid];
    __syncthreads();
    int t = blockIdx.x * 256 + tid;
    if (t >= 1000) return;
    float ex[5], ssum = 0.f;
    #pragma unroll
    for (int c = 0; c < 5; ++c) {
        float2 gu = *(const float2*)&gumbel[(size_t)(((b * 5 + c) * 1000) + t) * 2];
        float arg = (2.f * spv[c] - 1.f + gu.y - gu.x) * 10.0f;
        float gt  = 1.f / (1.f + __expf(-arg));
        out_gt[(b * 5 + c) * 1000 + t] = gt;
        float e = __expf(gt);
        ex[c] = e; ssum += e;
    }
    float inv = 1.f / ssum;
    float lg[10];
    #pragma unroll
    for (int k = 0; k < 10; ++k) lg[k] = b_mlp[k];
    #pragma unroll
    for (int c = 0; c < 5; ++c) {
        float v = ex[c] * inv;
        #pragma unroll
        for (int k = 0; k < 10; ++k) lg[k] = fmaf(v, sM[c * 10 + k], lg[k]);
    }
    float mx = 0.f;
    #pragma unroll
    for (int k = 0; k < 10; ++k) { lg[k] = fmaxf(lg[k], 0.f); mx = fmaxf(mx, lg[k]); }
    float se = 0.f;
    #pragma unroll
    for (int k = 0; k < 10; ++k) { lg[k] = __expf(lg[k] - mx); se += lg[k]; }
    float invs = 1.f / se;
    float2 outv[5];
    #pragma unroll
    for (int k = 0; k < 10; ++k) ((float*)outv)[k] = lg[k] * invs;
    float2* dst = (float2*)&out_rs[(size_t)t * 1280 + b * 10];
    #pragma unroll
    for (int j = 0; j < 5; ++j) dst[j] = outv[j];
}

extern "C" void kernel_launch(void* const* d_in, const int* in_sizes, int n_in,
                              void* d_out, int out_size, void* d_ws, size_t ws_size,
                              hipStream_t stream) {
    const float* feats   = (const float*)d_in[0];
    const float* W_adapt = (const float*)d_in[1];
    const float* b_adapt = (const float*)d_in[2];
    const float* W_ch    = (const float*)d_in[3];
    const float* b_ch    = (const float*)d_in[4];
    const float* W_gate  = (const float*)d_in[5];
    const float* b_gate  = (const float*)d_in[6];
    const float* W_mlp   = (const float*)d_in[7];
    const float* b_mlp   = (const float*)d_in[8];
    const float* gumbel  = (const float*)d_in[9];

    float* out    = (float*)d_out;
    float* out_rs = out;                  // (T,B,K)  1,280,000
    float* out_gt = out + 1280000;        // (B,C,T)    640,000
    float* out_pt = out + 1920000;        // (B,C,1)        640

    float* ws  = (float*)d_ws;
    float* pA  = ws;                      // 10*128*512 = 655,360
    float* r_b = pA + 655360;             //  65,536
    float* hT  = r_b + 65536;             // 5*128*512 = 327,680
    float* p   = hT + 327680;             //     640
    float* M   = p + 640;                 //   6,400

    void* args[] = {
        (void*)&feats, (void*)&W_adapt, (void*)&b_adapt, (void*)&W_ch,
        (void*)&b_ch, (void*)&W_gate, (void*)&b_gate, (void*)&W_mlp,
        (void*)&b_mlp, (void*)&gumbel,
        (void*)&pA, (void*)&r_b, (void*)&hT, (void*)&p, (void*)&M,
        (void*)&out_rs, (void*)&out_gt, (void*)&out_pt
    };
    hipError_t err = hipLaunchCooperativeKernel((const void*)mega,
                                                dim3(NBLK), dim3(NTHR),
                                                args, 0, stream);
    if (err != hipSuccess) {
        // fallback: proven 5-kernel chain
        kA <<<dim3(32, 10),   256, 0, stream>>>(feats, W_adapt, pA);
        kRA<<<256,            256, 0, stream>>>(pA, b_adapt, b_ch, r_b, hT);
        kB <<<dim3(16, 4, 5), 256, 0, stream>>>(r_b, W_ch, hT);
        kG <<<160,            256, 0, stream>>>(hT, W_gate, W_mlp, b_gate, p, M, out_pt);
        kC <<<dim3(4, 128),   256, 0, stream>>>(p, M, b_mlp, gumbel, out_rs, out_gt);
    }
}

// Round 7
// 43.513 us; speedup vs baseline: 11.1658x; 11.1658x over previous
//
#include <hip/hip_runtime.h>
#include <hip/hip_bf16.h>
#include <math.h>

// B=128, F_IN=1000, D=512, K=10, C=5, T=1000, TAU=0.1
// Contraction: logits_s[b,t,k] = sum_c v[b,c,t]*M[b,c,k], M = h @ W_mlp.
// R7: weight-traffic-optimal GEMMs — every block spans ALL 128 b, so each
// weight element is fetched exactly once (was 16-32x redundant = 84/64 MB).
// LDS-staged both operands; 8b x 2e register tile per thread (VALU-bound).
// 5 nodes (node overhead measured ~0; exec is everything):
//   kA  (16 e-chunks x 20 k-splits) -> pA[20][128][512]
//   kRA reduce 20 partials + bias + relu -> r_b
//   kB  (16 e-chunks x 8 d-splits x 5 c) -> pB[8][5][128][512]
//   kG  wave per (b,c): reduce 8 partials -> h -> gate p, M
//   kC  per (b,t): gumbel-sigmoid, softmax_c, MLP, softmax_k

// ---- adapt partials ----
__global__ __launch_bounds__(256) void kA(const float* __restrict__ feats,
                                          const float* __restrict__ W_adapt,
                                          float* __restrict__ pA) {
    __shared__ float fls[128 * 50];   // [b][k] b-major
    __shared__ float wls[50 * 32];    // [k][e] linear
    const int tid = threadIdx.x;
    const int e0 = blockIdx.x * 32;
    const int s  = blockIdx.y;
    const int k0 = s * 50;

    #pragma unroll
    for (int it = 0; it < 25; ++it) {          // 6400 = 25*256
        int idx = it * 256 + tid;
        int b_l = idx / 50, k_l = idx - b_l * 50;
        fls[idx] = feats[b_l * 1000 + k0 + k_l];
    }
    #pragma unroll
    for (int it = 0; it < 7; ++it) {           // 1600 elems
        int idx = it * 256 + tid;
        if (idx < 1600)
            wls[idx] = W_adapt[(k0 + (idx >> 5)) * 512 + e0 + (idx & 31)];
    }
    __syncthreads();

    const int ep = tid & 15, bg = tid >> 4;    // 16 e-pairs x 16 b-groups
    float2 acc[8] = {};
    const float* fb = &fls[bg * 8 * 50];
    const float* wb = &wls[ep * 2];
    #pragma unroll 2
    for (int k = 0; k < 50; ++k) {
        float2 w = *(const float2*)&wb[k * 32];
        #pragma unroll
        for (int i = 0; i < 8; ++i) {
            float r = fb[i * 50 + k];          // LDS broadcast
            acc[i].x = fmaf(r, w.x, acc[i].x);
            acc[i].y = fmaf(r, w.y, acc[i].y);
        }
    }
    #pragma unroll
    for (int i = 0; i < 8; ++i)
        *(float2*)&pA[(s * 128 + bg * 8 + i) * 512 + e0 + ep * 2] = acc[i];
}

// ---- reduce 20 partials + bias + relu ----
__global__ __launch_bounds__(256) void kRA(const float* __restrict__ pA,
                                           const float* __restrict__ b_adapt,
                                           float* __restrict__ r_b) {
    int i = blockIdx.x * 256 + threadIdx.x;    // < 65536
    float acc = b_adapt[i & 511];
    #pragma unroll
    for (int s = 0; s < 20; ++s) acc += pA[s * 65536 + i];
    r_b[i] = fmaxf(acc, 0.f);
}

// ---- channel partials: pB[ds][c][b][e], weights fetched once ----
__global__ __launch_bounds__(256) void kB(const float* __restrict__ r_b,
                                          const float* __restrict__ W_ch,
                                          float* __restrict__ pB) {
    __shared__ float rbs[128 * 64];   // [b][d] b-major (conflict-free store)
    __shared__ float wls[64 * 32];    // [d][e] linear
    const int tid = threadIdx.x;
    const int e0 = blockIdx.x * 32;
    const int ds = blockIdx.y;
    const int c  = blockIdx.z;
    const int d0 = ds * 64;

    #pragma unroll
    for (int it = 0; it < 32; ++it) {          // 8192 = 32*256
        int idx = it * 256 + tid;
        rbs[idx] = r_b[(idx >> 6) * 512 + d0 + (idx & 63)];
    }
    #pragma unroll
    for (int it = 0; it < 8; ++it) {           // 2048 = 8*256
        int idx = it * 256 + tid;
        wls[idx] = W_ch[((size_t)(c * 512 + d0 + (idx >> 5))) * 512 + e0 + (idx & 31)];
    }
    __syncthreads();

    const int ep = tid & 15, bg = tid >> 4;
    float2 acc[8] = {};
    const float* rb = &rbs[bg * 8 * 64];
    const float* wb = &wls[ep * 2];
    #pragma unroll 2
    for (int d = 0; d < 64; ++d) {
        float2 w = *(const float2*)&wb[d * 32];
        #pragma unroll
        for (int i = 0; i < 8; ++i) {
            float r = rb[i * 64 + d];          // LDS broadcast
            acc[i].x = fmaf(r, w.x, acc[i].x);
            acc[i].y = fmaf(r, w.y, acc[i].y);
        }
    }
    #pragma unroll
    for (int i = 0; i < 8; ++i)
        *(float2*)&pB[((ds * 5 + c) * 128 + bg * 8 + i) * 512 + e0 + ep * 2] = acc[i];
}

// ---- gate + M: wave per (b,c), reduce 8 partials inline ----
__global__ __launch_bounds__(256) void kG(const float* __restrict__ pB,
                                          const float* __restrict__ b_ch,
                                          const float* __restrict__ W_gate,
                                          const float* __restrict__ W_mlp,
                                          const float* __restrict__ b_gate,
                                          float* __restrict__ p,
                                          float* __restrict__ M,
                                          float* __restrict__ out_pt) {
    int wv = threadIdx.x >> 6, lane = threadIdx.x & 63;
    int pair = blockIdx.x * 4 + wv;    // < 640
    int b = pair / 5, c = pair % 5;
    float gs = 0.f, am[10] = {};
    #pragma unroll
    for (int i = 0; i < 8; ++i) {
        int e = i * 64 + lane;
        float hs = b_ch[c * 512 + e];
        #pragma unroll
        for (int s = 0; s < 8; ++s)
            hs += pB[((s * 5 + c) * 128 + b) * 512 + e];
        float h = fmaxf(hs, 0.f);
        gs = fmaf(h, W_gate[c * 512 + e], gs);
        const float* wm = &W_mlp[e * 10];
        #pragma unroll
        for (int k = 0; k < 10; ++k) am[k] = fmaf(h, wm[k], am[k]);
    }
    #pragma unroll
    for (int off = 32; off; off >>= 1) {
        gs += __shfl_xor(gs, off);
        #pragma unroll
        for (int k = 0; k < 10; ++k) am[k] += __shfl_xor(am[k], off);
    }
    if (lane == 0) {
        float pv = 1.f / (1.f + __expf(-(gs + b_gate[c])));
        p[b * 5 + c] = pv;
        out_pt[b * 5 + c] = pv;
        #pragma unroll
        for (int k = 0; k < 10; ++k) M[(b * 5 + c) * 10 + k] = am[k];
    }
}

// ---- epilogue: per (t-chunk, b) ----
__global__ __launch_bounds__(256) void kC(const float* __restrict__ p,
                                          const float* __restrict__ M,
                                          const float* __restrict__ b_mlp,
                                          const float* __restrict__ gumbel,
                                          float* __restrict__ out_rs,
                                          float* __restrict__ out_gt) {
    __shared__ float spv[5];
    __shared__ float sM[50];
    int tid = threadIdx.x;
    int b = blockIdx.y;
    if (tid < 50) sM[tid] = M[b * 50 + tid];
    if (tid < 5)  spv[tid] = p[b * 5 + tid];
    __syncthreads();

    int t = blockIdx.x * 256 + tid;
    if (t >= 1000) return;
    float ex[5], ssum = 0.f;
    #pragma unroll
    for (int c = 0; c < 5; ++c) {
        float2 gu = *(const float2*)&gumbel[(size_t)(((b * 5 + c) * 1000) + t) * 2];
        float arg = (2.f * spv[c] - 1.f + gu.y - gu.x) * 10.0f;  // /tau
        float gt  = 1.f / (1.f + __expf(-arg));
        out_gt[(b * 5 + c) * 1000 + t] = gt;
        float e = __expf(gt);
        ex[c] = e; ssum += e;
    }
    float inv = 1.f / ssum;
    float lg[10];
    #pragma unroll
    for (int k = 0; k < 10; ++k) lg[k] = b_mlp[k];
    #pragma unroll
    for (int c = 0; c < 5; ++c) {
        float v = ex[c] * inv;
        #pragma unroll
        for (int k = 0; k < 10; ++k) lg[k] = fmaf(v, sM[c * 10 + k], lg[k]);
    }
    float mx = 0.f;
    #pragma unroll
    for (int k = 0; k < 10; ++k) { lg[k] = fmaxf(lg[k], 0.f); mx = fmaxf(mx, lg[k]); }
    float se = 0.f;
    #pragma unroll
    for (int k = 0; k < 10; ++k) { lg[k] = __expf(lg[k] - mx); se += lg[k]; }
    float invs = 1.f / se;
    float2 outv[5];
    #pragma unroll
    for (int k = 0; k < 10; ++k) ((float*)outv)[k] = lg[k] * invs;
    float2* dst = (float2*)&out_rs[(size_t)t * 1280 + b * 10];
    #pragma unroll
    for (int j = 0; j < 5; ++j) dst[j] = outv[j];
}

extern "C" void kernel_launch(void* const* d_in, const int* in_sizes, int n_in,
                              void* d_out, int out_size, void* d_ws, size_t ws_size,
                              hipStream_t stream) {
    const float* feats   = (const float*)d_in[0];
    const float* W_adapt = (const float*)d_in[1];
    const float* b_adapt = (const float*)d_in[2];
    const float* W_ch    = (const float*)d_in[3];
    const float* b_ch    = (const float*)d_in[4];
    const float* W_gate  = (const float*)d_in[5];
    const float* b_gate  = (const float*)d_in[6];
    const float* W_mlp   = (const float*)d_in[7];
    const float* b_mlp   = (const float*)d_in[8];
    const float* gumbel  = (const float*)d_in[9];

    float* out    = (float*)d_out;
    float* out_rs = out;                  // (T,B,K)  1,280,000
    float* out_gt = out + 1280000;        // (B,C,T)    640,000
    float* out_pt = out + 1920000;        // (B,C,1)        640

    float* ws  = (float*)d_ws;
    float* pA  = ws;                      // 20*128*512   = 1,310,720
    float* pB  = pA + 1310720;            // 8*5*128*512  = 2,621,440
    float* r_b = pB + 2621440;            //    65,536
    float* p   = r_b + 65536;             //       640
    float* M   = p + 640;                 //     6,400   (~16 MB total, ws=256MB)

    kA <<<dim3(16, 20),   256, 0, stream>>>(feats, W_adapt, pA);
    kRA<<<256,            256, 0, stream>>>(pA, b_adapt, r_b);
    kB <<<dim3(16, 8, 5), 256, 0, stream>>>(r_b, W_ch, pB);
    kG <<<160,            256, 0, stream>>>(pB, b_ch, W_gate, W_mlp, b_gate, p, M, out_pt);
    kC <<<dim3(4, 128),   256, 0, stream>>>(p, M, b_mlp, gumbel, out_rs, out_gt);
}